// Round 1
// baseline (1239.786 us; speedup 1.0000x reference)
//
#include <hip/hip_runtime.h>
#include <math.h>

#define NPTS 4096
#define NCH  1024
#define HH 128
#define WW 128
#define SLICE (HH*WW)

struct WsPtrs {
  double* Hg;      // 27 doubles: H upper-tri (21, k<=l row-major) then g (6)
  float* state;    // [0..8]=R, [9..11]=t, [12]=lam, [13]=prev_cost, [14..22]=R_new, [23..25]=t_new
  float* p3d0;     // 3*NPTS SoA (x,y,z)
  float* idx0x;    // NPTS
  float* idx0y;    // NPTS
  float* nidxx;    // NPTS (clipped sample x at tentative state)
  float* nidxy;    // NPTS
  float* np2;      // 2*NPTS interleaved (unclipped p2 at tentative state)
  float* best;     // 2*NPTS interleaved
  float* Aarr;     // 7*NPTS SoA: a,b,c,d,X,Y,Z
  float* part;     // 28*1024 per-block partials (21 H, 6 g, 1 cost)
};

// mode 0: init (invert r, relative=q@rinv, pts3d0, idx0) ; mode 1: LM solve+update
__global__ __launch_bounds__(256) void prep_kernel(
    int mode, const float* __restrict__ pts2d, const float* __restrict__ pts3d,
    const float* __restrict__ qm, const float* __restrict__ rm,
    const float* __restrict__ K1, WsPtrs ws)
{
  __shared__ float sRt[12];
  const int t = threadIdx.x;
  if (t == 0) {
    float Rn[9], tn[3];
    if (mode == 0) {
      // 4x4 inverse of r (double Gauss-Jordan; r is ~identity in data)
      double M[4][8];
      for (int i=0;i<4;i++) for (int j=0;j<4;j++){ M[i][j]=rm[i*4+j]; M[i][4+j]=(i==j)?1.0:0.0; }
      for (int k=0;k<4;k++){
        int p=k; double bv=fabs(M[k][k]);
        for (int i=k+1;i<4;i++){ double v=fabs(M[i][k]); if(v>bv){bv=v;p=i;} }
        if (p!=k) for (int j=0;j<8;j++){ double tmp=M[k][j]; M[k][j]=M[p][j]; M[p][j]=tmp; }
        double pv = M[k][k];
        for (int j=0;j<8;j++) M[k][j] /= pv;
        for (int i=0;i<4;i++) if (i!=k){
          double f2=M[i][k];
          for (int j=0;j<8;j++) M[i][j] -= f2*M[k][j];
        }
      }
      float rel[16];
      for (int i=0;i<4;i++) for (int j=0;j<4;j++){
        float s=0.f;
        for (int k=0;k<4;k++) s += qm[i*4+k]*(float)M[k][4+j];
        rel[i*4+j]=s;
      }
      for (int i=0;i<3;i++) for (int j=0;j<3;j++) Rn[i*3+j]=rel[i*4+j];
      tn[0]=rel[3]; tn[1]=rel[7]; tn[2]=rel[11];
      for (int k=0;k<9;k++) ws.state[k]=Rn[k];
      for (int k=0;k<3;k++) ws.state[9+k]=tn[k];
      ws.state[12] = 0.01f;   // INIT_LAMBDA; prev_cost set by commit(force)
    } else {
      // assemble Hd, solve Hd x = g, delta = -x
      double M[6][7]; int p=0;
      double Hf[6][6];
      for (int k=0;k<6;k++) for (int l=k;l<6;l++){ double v=ws.Hg[p++]; Hf[k][l]=v; Hf[l][k]=v; }
      double lam = (double)ws.state[12];
      for (int k=0;k<6;k++){
        for (int l=0;l<6;l++) M[k][l]=Hf[k][l];
        M[k][6]=ws.Hg[21+k];
      }
      for (int k=0;k<6;k++) M[k][k] = M[k][k] + (M[k][k] + 1e-9)*lam;
      for (int k=0;k<6;k++){
        int pi=k; double bv=fabs(M[k][k]);
        for (int i=k+1;i<6;i++){ double v=fabs(M[i][k]); if(v>bv){bv=v;pi=i;} }
        if (pi!=k) for (int j=k;j<7;j++){ double tmp=M[k][j];M[k][j]=M[pi][j];M[pi][j]=tmp; }
        double pv=M[k][k];
        for (int i=k+1;i<6;i++){
          double f2=M[i][k]/pv;
          for (int j=k;j<7;j++) M[i][j]-=f2*M[k][j];
        }
      }
      double x[6];
      for (int k=5;k>=0;k--){
        double s=M[k][6];
        for (int j=k+1;j<6;j++) s-=M[k][j]*x[j];
        x[k]=s/M[k][k];
      }
      float dt0=(float)(-x[0]), dt1=(float)(-x[1]), dt2=(float)(-x[2]);
      float w0=(float)(-x[3]), w1=(float)(-x[4]), w2=(float)(-x[5]);
      // so3exp in fp32 (matches reference)
      float th2 = w0*w0+w1*w1+w2*w2;
      float th = sqrtf(fmaxf(th2, 1e-24f));
      float A_ = (th2 < 1e-16f) ? 1.f : (sinf(th)/th);
      float B_ = (th2 < 1e-16f) ? 0.5f : ((1.f - cosf(th)) / fmaxf(th2, 1e-24f));
      float Kx[9] = {0.f,-w2,w1,  w2,0.f,-w0,  -w1,w0,0.f};
      float K2[9];
      for (int i=0;i<3;i++) for (int j=0;j<3;j++){
        float s=0.f; for (int k=0;k<3;k++) s+=Kx[i*3+k]*Kx[k*3+j];
        K2[i*3+j]=s;
      }
      float dr[9];
      for (int i=0;i<9;i++) dr[i] = ((i%4==0)?1.f:0.f) + A_*Kx[i] + B_*K2[i];
      float Rc[9], tc[3];
      for (int k=0;k<9;k++) Rc[k]=ws.state[k];
      for (int k=0;k<3;k++) tc[k]=ws.state[9+k];
      for (int i=0;i<3;i++) for (int j=0;j<3;j++){
        float s=0.f; for (int k=0;k<3;k++) s+=dr[i*3+k]*Rc[k*3+j];
        Rn[i*3+j]=s;
      }
      for (int i=0;i<3;i++){
        float s=0.f; for (int k=0;k<3;k++) s+=dr[i*3+k]*tc[k];
        tn[i]=s+((i==0)?dt0:(i==1)?dt1:dt2);
      }
    }
    for (int k=0;k<9;k++){ ws.state[14+k]=Rn[k]; sRt[k]=Rn[k]; }
    for (int k=0;k<3;k++){ ws.state[23+k]=tn[k]; sRt[9+k]=tn[k]; }
  }
  __syncthreads();
  const float R0=sRt[0],R1=sRt[1],R2=sRt[2],R3=sRt[3],R4=sRt[4],R5=sRt[5],R6=sRt[6],R7=sRt[7],R8=sRt[8];
  const float T0=sRt[9],T1=sRt[10],T2=sRt[11];
  const float fx=K1[0], cx=K1[2], fy=K1[4], cy=K1[5];
  for (int i=0;i<16;i++){
    int n = t + i*256;
    float px, py, pz;
    if (mode==0) {
      float X=pts3d[n*3+0], Y=pts3d[n*3+1], Z=pts3d[n*3+2];
      float hx = rm[0]*X + rm[1]*Y + rm[2]*Z + rm[3];
      float hy = rm[4]*X + rm[5]*Y + rm[6]*Z + rm[7];
      float hz = rm[8]*X + rm[9]*Y + rm[10]*Z + rm[11];
      float hw = rm[12]*X + rm[13]*Y + rm[14]*Z + rm[15];
      px = hx/hw; py = hy/hw; pz = hz/hw;
      ws.p3d0[n]=px; ws.p3d0[NPTS+n]=py; ws.p3d0[2*NPTS+n]=pz;
      ws.idx0x[n]=pts2d[n*2+0]*0.125f;
      ws.idx0y[n]=pts2d[n*2+1]*0.125f;
    } else {
      px=ws.p3d0[n]; py=ws.p3d0[NPTS+n]; pz=ws.p3d0[2*NPTS+n];
    }
    float X = R0*px + R1*py + R2*pz + T0;
    float Y = R3*px + R4*py + R5*pz + T1;
    float Z = R6*px + R7*py + R8*pz + T2;
    float p2x = (fx*X + cx*Z)/Z;
    float p2y = (fy*Y + cy*Z)/Z;
    ws.np2[2*n]=p2x; ws.np2[2*n+1]=p2y;
    ws.nidxx[n] = fminf(fmaxf(p2x*0.125f, 0.f), (float)(WW-1));
    ws.nidxy[n] = fminf(fmaxf(p2y*0.125f, 0.f), (float)(HH-1));
    // J_h_p rows (already /z/8): [a,0,c],[0,b,d]
    float a = (fx/Z)*0.125f;
    float b = (fy/Z)*0.125f;
    float c = ((-fx*X)/Z)/Z*0.125f;
    float d = ((-fy*Y)/Z)/Z*0.125f;
    ws.Aarr[n]=a; ws.Aarr[NPTS+n]=b; ws.Aarr[2*NPTS+n]=c; ws.Aarr[3*NPTS+n]=d;
    ws.Aarr[4*NPTS+n]=X; ws.Aarr[5*NPTS+n]=Y; ws.Aarr[6*NPTS+n]=Z;
  }
}

// One block per channel. Phase A: stage imgf1 slice, sample value + Sobel grads.
// Phase B: stage imgf0 slice, recompute feat0, accumulate H/g/cost partials.
__global__ __launch_bounds__(256) void big_kernel(
    const float* __restrict__ img0, const float* __restrict__ img1, WsPtrs ws)
{
  __shared__ __align__(16) float tile[SLICE];
  const int c = blockIdx.x;
  const int t = threadIdx.x;
  {
    const float4* g4 = reinterpret_cast<const float4*>(img1 + (size_t)c*SLICE);
    float4* t4 = reinterpret_cast<float4*>(tile);
    #pragma unroll
    for (int i=0;i<16;i++) t4[t + i*256] = g4[t + i*256];
  }
  __syncthreads();

  float f1a[16], gxa[16], gya[16];
  #pragma unroll
  for (int i=0;i<16;i++){
    int n = t + i*256;
    float x = ws.nidxx[n], y = ws.nidxy[n];
    float x0f = floorf(x), y0f = floorf(y);
    float wx = x - x0f, wy = y - y0f;
    int xi = (int)x0f, yi = (int)y0f;
    float v[4][4];
    if (xi>=1 && xi<=WW-3 && yi>=1 && yi<=HH-3) {
      int base = (yi-1)*WW + (xi-1);
      #pragma unroll
      for (int r=0;r<4;r++)
        #pragma unroll
        for (int cc=0;cc<4;cc++)
          v[r][cc] = tile[base + r*WW + cc];
    } else {
      // border: SAME-conv zero padding for the Sobel stencil
      #pragma unroll
      for (int r=0;r<4;r++){
        int ry = yi-1+r;
        bool okr = (ry>=0) && (ry<HH);
        int ryc = min(max(ry,0),HH-1);
        #pragma unroll
        for (int cc=0;cc<4;cc++){
          int rx = xi-1+cc;
          bool ok = okr && (rx>=0) && (rx<WW);
          int rxc = min(max(rx,0),WW-1);
          float val = tile[ryc*WW + rxc];
          v[r][cc] = ok ? val : 0.f;
        }
      }
    }
    float D1[4], D2[4], E0a[4], E1a[4];
    #pragma unroll
    for (int r=0;r<4;r++){ D1[r]=v[r][2]-v[r][0]; D2[r]=v[r][3]-v[r][1]; }
    #pragma unroll
    for (int cc=0;cc<4;cc++){ E0a[cc]=v[2][cc]-v[0][cc]; E1a[cc]=v[3][cc]-v[1][cc]; }
    float gx00 = D1[0] + 2.f*D1[1] + D1[2];   // (y0,x0)
    float gx01 = D2[0] + 2.f*D2[1] + D2[2];   // (y0,x1)
    float gx10 = D1[1] + 2.f*D1[2] + D1[3];   // (y1,x0)
    float gx11 = D2[1] + 2.f*D2[2] + D2[3];   // (y1,x1)
    float gy00 = E0a[0] + 2.f*E0a[1] + E0a[2];
    float gy01 = E0a[1] + 2.f*E0a[2] + E0a[3];
    float gy10 = E1a[0] + 2.f*E1a[1] + E1a[2];
    float gy11 = E1a[1] + 2.f*E1a[2] + E1a[3];
    float w00=(1.f-wx)*(1.f-wy), w10=wx*(1.f-wy), w01=(1.f-wx)*wy, w11=wx*wy;
    f1a[i] = w00*v[1][1] + w10*v[1][2] + w01*v[2][1] + w11*v[2][2];
    gxa[i] = 0.125f*(w00*gx00 + w10*gx01 + w01*gx10 + w11*gx11);
    gya[i] = 0.125f*(w00*gy00 + w10*gy01 + w01*gy10 + w11*gy11);
  }
  __syncthreads();
  {
    const float4* g4 = reinterpret_cast<const float4*>(img0 + (size_t)c*SLICE);
    float4* t4 = reinterpret_cast<float4*>(tile);
    #pragma unroll
    for (int i=0;i<16;i++) t4[t + i*256] = g4[t + i*256];
  }
  __syncthreads();

  float acc[28];
  #pragma unroll
  for (int a=0;a<28;a++) acc[a]=0.f;
  #pragma unroll
  for (int i=0;i<16;i++){
    int n = t + i*256;
    float x = ws.idx0x[n], y = ws.idx0y[n];
    float x0f=floorf(x), y0f=floorf(y);
    float wx=x-x0f, wy=y-y0f;
    int xi=min(max((int)x0f,0),WW-1);
    int yi=min(max((int)y0f,0),HH-1);
    int x1=min(xi+1,WW-1), y1=min(yi+1,HH-1);
    float f00=tile[yi*WW+xi], f10=tile[yi*WW+x1], f01=tile[y1*WW+xi], f11=tile[y1*WW+x1];
    float feat0 = f00*(1.f-wx)*(1.f-wy) + f10*wx*(1.f-wy) + f01*(1.f-wx)*wy + f11*wx*wy;
    float e = f1a[i] - feat0;
    float a_=ws.Aarr[n], b_=ws.Aarr[NPTS+n], c_=ws.Aarr[2*NPTS+n], d_=ws.Aarr[3*NPTS+n];
    float X=ws.Aarr[4*NPTS+n], Y=ws.Aarr[5*NPTS+n], Z=ws.Aarr[6*NPTS+n];
    float T0 = gxa[i]*a_;
    float T1 = gya[i]*b_;
    float T2 = gxa[i]*c_ + gya[i]*d_;
    float jv[6];
    jv[0]=T0; jv[1]=T1; jv[2]=T2;
    jv[3] = -T1*Z + T2*Y;
    jv[4] =  T0*Z - T2*X;
    jv[5] = -T0*Y + T1*X;
    int p=0;
    #pragma unroll
    for (int k=0;k<6;k++)
      #pragma unroll
      for (int l=k;l<6;l++)
        { acc[p] += jv[k]*jv[l]; p++; }
    #pragma unroll
    for (int k=0;k<6;k++) acc[21+k] += e*jv[k];
    acc[27] += e*e;
  }
  // block reduce 28 accumulators (reuse tile as scratch)
  #pragma unroll
  for (int a=0;a<28;a++){
    float vv=acc[a];
    for (int off=32; off>0; off>>=1) vv += __shfl_down(vv, off, 64);
    acc[a]=vv;
  }
  __syncthreads();
  int wave = t>>6, lane = t&63;
  if (lane==0){
    #pragma unroll
    for (int a=0;a<28;a++) tile[wave*28+a]=acc[a];
  }
  __syncthreads();
  if (t<28){
    float s = tile[t]+tile[28+t]+tile[56+t]+tile[84+t];
    ws.part[t*1024 + c] = s;
  }
}

__global__ __launch_bounds__(256) void commit_kernel(int force, WsPtrs ws, float* __restrict__ dout)
{
  const int t = threadIdx.x;
  __shared__ float red[4*28];
  __shared__ double stot[28];
  __shared__ int sacc;
  float loc[28];
  #pragma unroll
  for (int a=0;a<28;a++){
    const float* pa = ws.part + a*1024;
    loc[a] = pa[t] + pa[t+256] + pa[t+512] + pa[t+768];
  }
  #pragma unroll
  for (int a=0;a<28;a++){
    float vv=loc[a];
    for (int off=32;off>0;off>>=1) vv += __shfl_down(vv,off,64);
    loc[a]=vv;
  }
  int wave=t>>6, lane=t&63;
  if (lane==0){
    #pragma unroll
    for (int a=0;a<28;a++) red[wave*28+a]=loc[a];
  }
  __syncthreads();
  if (t<28) stot[t] = (double)red[t]+(double)red[28+t]+(double)red[56+t]+(double)red[84+t];
  __syncthreads();
  if (t==0){
    float cost_new = (float)(stot[27] / (double)NPTS);
    int acc = force || (cost_new <= ws.state[13]);
    if (acc){
      ws.state[13]=cost_new;
      for (int k=0;k<9;k++) ws.state[k]=ws.state[14+k];
      for (int k=0;k<3;k++) ws.state[9+k]=ws.state[23+k];
      for (int a=0;a<27;a++) ws.Hg[a]=stot[a];
    }
    if (!force){
      float l = ws.state[12]*(acc?0.1f:10.f);
      ws.state[12]=fminf(fmaxf(l,1e-6f),100.f);
    }
    sacc=acc;
  }
  __syncthreads();
  int acc=sacc;
  float2* best2=(float2*)ws.best;
  const float2* np22=(const float2*)ws.np2;
  float2* out2=(float2*)dout;
  #pragma unroll
  for (int i=0;i<16;i++){
    int n=t+i*256;
    if (acc) best2[n]=np22[n];
    out2[n]=best2[n];
  }
}

extern "C" void kernel_launch(void* const* d_in, const int* in_sizes, int n_in,
                              void* d_out, int out_size, void* d_ws, size_t ws_size,
                              hipStream_t stream) {
  (void)in_sizes; (void)n_in; (void)out_size; (void)ws_size;
  const float* img0  = (const float*)d_in[0];
  const float* img1  = (const float*)d_in[1];
  const float* pts2d = (const float*)d_in[2];
  const float* pts3d = (const float*)d_in[3];
  const float* qm    = (const float*)d_in[4];
  const float* rm    = (const float*)d_in[5];
  const float* K1    = (const float*)d_in[6];
  float* out = (float*)d_out;

  char* w = (char*)d_ws;
  WsPtrs ws;
  ws.Hg    = (double*)w;               // 216 B used, reserve 256
  ws.state = (float*)(w + 256);        // 104 B used, reserve 256
  float* f = (float*)(w + 512);
  ws.p3d0  = f; f += 3*NPTS;
  ws.idx0x = f; f += NPTS;
  ws.idx0y = f; f += NPTS;
  ws.nidxx = f; f += NPTS;
  ws.nidxy = f; f += NPTS;
  ws.np2   = f; f += 2*NPTS;
  ws.best  = f; f += 2*NPTS;
  ws.Aarr  = f; f += 7*NPTS;
  ws.part  = f; f += 28*1024;          // total ~410 KB

  // init: state, pts3d0, idx0, tentative = init state
  prep_kernel<<<1,256,0,stream>>>(0, pts2d, pts3d, qm, rm, K1, ws);
  // H,g,cost at init state; force-commit (prev_cost=cost_init, best=p2_init)
  big_kernel<<<NCH,256,0,stream>>>(img0, img1, ws);
  commit_kernel<<<1,256,0,stream>>>(1, ws, out);
  for (int it=0; it<10; ++it){
    prep_kernel<<<1,256,0,stream>>>(1, pts2d, pts3d, qm, rm, K1, ws);
    big_kernel<<<NCH,256,0,stream>>>(img0, img1, ws);
    commit_kernel<<<1,256,0,stream>>>(0, ws, out);
  }
}